// Round 4
// baseline (374.415 us; speedup 1.0000x reference)
//
#include <hip/hip_runtime.h>
#include <math.h>

// power[b,t,d] = b_mag_d^2 * |S|^2,  S[t] = r_d*S[t-1] + x[b,t],
// r_d = e^{-softplus(alpha_raw_d)} * e^{i*omega_d}.  b_phase cancels in |H|^2.
//
// R5: two-dispatch split. R0 (scalar stores, no barriers) and R4 (dwordx4 NT
// stores, 2x waves) both sat at ~2.4 TB/s effective write BW, while the
// harness fill hits 6.3 TB/s at 10% occupancy -> store micro-structure and
// occupancy are NOT the limiter. Remaining suspect: the globally synchronized
// zero-store warm-up phase (~40 us, all blocks in lockstep) plus warm-up
// interleaved ahead of every store stream. Fix: hoist ALL warm-up into a
// small state-pass (A) that writes chunk-boundary states to d_ws; the main
// pass (B) is then a continuous fill-like streamer: load state, 400 steps,
// 400 stores, no barriers in the loop, unbounded store pipelining.

#define BB 8
#define LL 80000
#define DD 128
#define CHUNK 400         // outputs per block in pass B; CHUNK*NCHUNK == LL
#define NCHUNK 200
#define KMAX 1152         // warm-up taps, multiple of 4
#define NT 128            // one thread per channel d

#define STEP(xv)                                   \
    {                                              \
        float t1 = fmaf(-ei, si, (xv));            \
        float nr = fmaf(er, sr, t1);               \
        float ni = fmaf(er, si, ei * sr);          \
        sr = nr; si = ni;                          \
    }

// ---------------- Pass A: chunk-boundary states ----------------
// Block (c,b): run K warm-up steps over x[c*400-K .. c*400) from zero state,
// store S into ws[(b*NCHUNK+c)*DD + d]. Chunk 0 gets the zero-padded window
// (state == 0 contribution), matching the reference's K-tap truncation.
__global__ __launch_bounds__(NT) void sstfr_state(
    const float* __restrict__ x,          // (B, L)
    const float* __restrict__ omega,      // (D,)
    const float* __restrict__ alpha_raw,  // (D,)
    const int*   __restrict__ Kp,         // scalar
    float2*      __restrict__ ws)         // (B*NCHUNK, D)
{
    __shared__ __align__(16) float xs[KMAX];

    const int d = threadIdx.x;
    const int c = blockIdx.x;
    const int b = blockIdx.y;

    int K = Kp[0];
    K = (K + 3) & ~3;
    if (K > KMAX) K = KMAX;                // deterministic K=1152; clamp safety

    const int base = c * CHUNK - K;        // window start (may be negative)
    const float* xb = x + (size_t)b * LL;

    for (int i = d; i < K; i += NT) {
        const int idx = base + i;
        xs[i] = (idx >= 0) ? xb[idx] : 0.0f;   // idx < LL always (c*400 <= L)
    }
    __syncthreads();

    const float w     = omega[d];
    const float alpha = -log1pf(expf(alpha_raw[d]));   // -softplus
    const float ea    = expf(alpha);
    const float er    = ea * cosf(w);
    const float ei    = ea * sinf(w);

    float sr = 0.0f, si = 0.0f;

    const float4* x4 = (const float4*)xs;
    const int g0 = K >> 2;                 // 288 groups

    float4 cur = x4[0];
    for (int q = 0; q < g0 - 1; ++q) {     // prefetch next group
        float4 nxt = x4[q + 1];            // q+1 <= g0-1: in bounds
        STEP(cur.x) STEP(cur.y) STEP(cur.z) STEP(cur.w)
        cur = nxt;
    }
    STEP(cur.x) STEP(cur.y) STEP(cur.z) STEP(cur.w)

    ws[((size_t)b * NCHUNK + c) * DD + d] = make_float2(sr, si);
}

// ---------------- Pass B: continuous streamer ----------------
// Block (c,b): load exact boundary state, stage 400 x-samples, emit 400
// outputs. No warm-up, no barriers in the store loop -> store stream is
// continuous and deeply pipelined from ~cycle 0, like the fill kernel.
__global__ __launch_bounds__(NT) void sstfr_stream(
    const float* __restrict__ x,          // (B, L)
    const float* __restrict__ omega,      // (D,)
    const float* __restrict__ alpha_raw,  // (D,)
    const float* __restrict__ b_log_mag,  // (D,)
    const float2* __restrict__ ws,        // (B*NCHUNK, D)
    float*       __restrict__ out)        // (B, L, D)
{
    __shared__ __align__(16) float xs[CHUNK];

    const int d = threadIdx.x;
    const int c = blockIdx.x;
    const int b = blockIdx.y;

    const int t0 = c * CHUNK;
    const float* xb = x + (size_t)b * LL + t0;

    for (int i = d; i < CHUNK; i += NT)    // fully in-range
        xs[i] = xb[i];
    __syncthreads();

    const float w     = omega[d];
    const float alpha = -log1pf(expf(alpha_raw[d]));   // -softplus
    const float ea    = expf(alpha);
    const float er    = ea * cosf(w);
    const float ei    = ea * sinf(w);
    const float scale = expf(2.0f * b_log_mag[d]);     // b_mag^2

    const float2 s0 = ws[((size_t)b * NCHUNK + c) * DD + d];
    float sr = s0.x, si = s0.y;

    float* op = out + ((size_t)b * LL + t0) * DD + d;

    const float4* x4 = (const float4*)xs;
    const int gT = CHUNK >> 2;             // 100 groups

    float4 cur = x4[0];
    for (int q = 0; q < gT - 1; ++q) {
        float4 nxt = x4[q + 1];            // q+1 <= gT-1: in bounds
        STEP(cur.x) op[0 * DD] = scale * fmaf(sr, sr, si * si);
        STEP(cur.y) op[1 * DD] = scale * fmaf(sr, sr, si * si);
        STEP(cur.z) op[2 * DD] = scale * fmaf(sr, sr, si * si);
        STEP(cur.w) op[3 * DD] = scale * fmaf(sr, sr, si * si);
        op += 4 * DD;
        cur = nxt;
    }
    STEP(cur.x) op[0 * DD] = scale * fmaf(sr, sr, si * si);
    STEP(cur.y) op[1 * DD] = scale * fmaf(sr, sr, si * si);
    STEP(cur.z) op[2 * DD] = scale * fmaf(sr, sr, si * si);
    STEP(cur.w) op[3 * DD] = scale * fmaf(sr, sr, si * si);
}

extern "C" void kernel_launch(void* const* d_in, const int* in_sizes, int n_in,
                              void* d_out, int out_size, void* d_ws, size_t ws_size,
                              hipStream_t stream) {
    const float* x         = (const float*)d_in[0];
    const float* omega     = (const float*)d_in[1];
    const float* alpha_raw = (const float*)d_in[2];
    const float* b_log_mag = (const float*)d_in[3];
    // d_in[4] = b_phase: unused (cancels in |H|^2)
    const int*   Kp        = (const int*)d_in[5];
    float*  out = (float*)d_out;
    float2* ws  = (float2*)d_ws;           // needs B*NCHUNK*D*8 = 1.64 MB

    dim3 grid(NCHUNK, BB);
    dim3 block(NT);
    sstfr_state<<<grid, block, 0, stream>>>(x, omega, alpha_raw, Kp, ws);
    sstfr_stream<<<grid, block, 0, stream>>>(x, omega, alpha_raw, b_log_mag, ws, out);
}